// Round 1
// baseline (19253.403 us; speedup 1.0000x reference)
//
#include <hip/hip_runtime.h>
#include <hip/hip_bf16.h>

// RNN: B=256, T=256, I=64, H=2048, L=4, O=1
// h_t^l = tanh(W_ih^l @ inp + b_ih^l + W_hh^l @ h_{t-1}^l); out = h_T^{L-1} @ W_fc^T + b_fc
//
// Strategy: bf16 hi/lo split-3 MFMA GEMMs (fp32-equivalent accuracy), (t,l)
// anti-diagonal wavefront (4 concurrent layer-GEMMs per phase, 259 phases),
// parity-double-buffered hidden state, XOR-swizzled LDS tiles, reg-staged
// with next-chunk prefetch overlap.

typedef unsigned short u16;
typedef __attribute__((ext_vector_type(8))) short short8;
typedef __attribute__((ext_vector_type(4))) float f32x4;

#define T_N 256
#define B_N 256
#define I_N 64
#define H_N 2048
#define L_N 4

static constexpr size_t S0_ELE = 2048ull * 2112ull;           // layer0 combined W elems
static constexpr size_t SL_ELE = 2048ull * 4096ull;           // layers 1..3 each
static constexpr size_t WT_ELEMS = S0_ELE + 3ull * SL_ELE;    // 29,491,200
static constexpr size_t XS_ELEMS = 256ull * 256ull * 64ull;   // 4,194,304
static constexpr size_t HSLOT    = 256ull * 2048ull;          // one [B][H] slab
static constexpr size_t H_ELEMS  = 2ull * 4ull * HSLOT;       // parity x layer

__device__ __forceinline__ u16 f2bf(float v) {
  __hip_bfloat16 b = __float2bfloat16(v);
  u16 u; __builtin_memcpy(&u, &b, 2); return u;
}
__device__ __forceinline__ float bf2f(u16 u) {
  __hip_bfloat16 b; __builtin_memcpy(&b, &u, 2);
  return __bfloat162float(b);
}

// ---------------- prep: split fp32 weights into bf16 hi/lo, k-concatenated [n][k] ----
__global__ void prep_w(const float* __restrict__ W_ih0, const float* __restrict__ W_ih_rest,
                       const float* __restrict__ W_hh,
                       u16* __restrict__ wt_hi, u16* __restrict__ wt_lo) {
  const unsigned TOT = (unsigned)WT_ELEMS;
  for (unsigned i = blockIdx.x * 256u + threadIdx.x; i < TOT; i += gridDim.x * 256u) {
    int l, K, Kin; unsigned r;
    if (i < (unsigned)S0_ELE) { l = 0; r = i; K = 2112; Kin = 64; }
    else {
      unsigned j = i - (unsigned)S0_ELE;
      l = 1 + (int)(j / (unsigned)SL_ELE);
      r = j % (unsigned)SL_ELE; K = 4096; Kin = 2048;
    }
    unsigned n = r / (unsigned)K, k = r % (unsigned)K;
    float v;
    if ((int)k < Kin)
      v = (l == 0) ? W_ih0[(size_t)n * 64 + k]
                   : W_ih_rest[(((size_t)(l - 1)) * 2048 + n) * 2048 + k];
    else
      v = W_hh[(((size_t)l) * 2048 + n) * 2048 + (k - (unsigned)Kin)];
    u16 hi = f2bf(v);
    wt_hi[i] = hi;
    wt_lo[i] = f2bf(v - bf2f(hi));
  }
}

__global__ void prep_x(const float* __restrict__ x, u16* __restrict__ xs_hi, u16* __restrict__ xs_lo) {
  for (unsigned i = blockIdx.x * 256u + threadIdx.x; i < (unsigned)XS_ELEMS; i += gridDim.x * 256u) {
    float v = x[i];
    u16 hi = f2bf(v);
    xs_hi[i] = hi;
    xs_lo[i] = f2bf(v - bf2f(hi));
  }
}

// ---------------- one wavefront phase: all (l, t=s-l) layer-GEMMs -------------------
// Block tile 64(M=batch) x 128(N=h). 4 waves, wave-tile 32x64. KC=64.
// LDS: A(64x64) hi/lo + B(128x64) hi/lo = 48KB, XOR-swizzled 16B granules.
__launch_bounds__(256)
__global__ void phase_k(const u16* __restrict__ wt_hi, const u16* __restrict__ wt_lo,
                        const u16* __restrict__ xs_hi, const u16* __restrict__ xs_lo,
                        u16* __restrict__ h_hi, u16* __restrict__ h_lo,
                        const float* __restrict__ b_ih0, const float* __restrict__ b_ih_rest,
                        int s) {
  // XCD-aware decode: the 4 m-blocks sharing an n-tile land on one XCD (L2 reuse of W)
  int bid = blockIdx.x;
  int xcd = bid & 7, slot = bid >> 3;
  int tm = slot & 3;
  int tn = (xcd << 1) | ((slot >> 2) & 1);
  int l  = slot >> 3;
  int t  = s - l;
  if (t < 0 || t >= T_N) return;

  const int Kl  = (l == 0) ? 2112 : 4096;
  const int Kin = (l == 0) ? 64 : 2048;
  const size_t woff = (l == 0) ? 0ull : (S0_ELE + (size_t)(l - 1) * SL_ELE);
  const u16* wl_hi = wt_hi + woff;
  const u16* wl_lo = wt_lo + woff;

  const size_t ho_out  = ((size_t)((t & 1) * 4 + l)) * HSLOT;
  const size_t ho_self = ((size_t)(((t - 1) & 1) * 4 + l)) * HSLOT;
  const int lprev = (l > 0) ? (l - 1) : 0;
  const size_t ho_prevL = ((size_t)((t & 1) * 4 + lprev)) * HSLOT;

  __shared__ __align__(16) u16 Ahi[64 * 64];
  __shared__ __align__(16) u16 Alo[64 * 64];
  __shared__ __align__(16) u16 Bhi[128 * 64];
  __shared__ __align__(16) u16 Blo[128 * 64];

  const int tid = threadIdx.x;
  const int lane = tid & 63;
  const int l15 = lane & 15, g16 = lane >> 4;
  const int wid = tid >> 6;
  const int wave_m = (wid & 1) * 32, wave_n = (wid >> 1) * 64;

  f32x4 acc[2][4];
#pragma unroll
  for (int mi = 0; mi < 2; ++mi)
#pragma unroll
    for (int ni = 0; ni < 4; ++ni)
      acc[mi][ni] = (f32x4){0.f, 0.f, 0.f, 0.f};

  short8 sa_h[2], sa_l[2], sb_h[4], sb_l[4];  // reg staging

  auto load_chunk = [&](int kc) {
#pragma unroll
    for (int it = 0; it < 2; ++it) {  // A: 512 granules (64 rows x 8)
      int G = it * 256 + tid;
      int r = G >> 3, gl = G & 7;
      int kg = (kc << 6) + (gl << 3);
      int b = tm * 64 + r;
      const u16 *ph, *pl; size_t o;
      if (kg < Kin) {
        if (l == 0) { o = ((size_t)b * T_N + t) * I_N + kg; ph = xs_hi; pl = xs_lo; }
        else        { o = ho_prevL + (size_t)b * H_N + kg;  ph = h_hi;  pl = h_lo; }
      } else        { o = ho_self + (size_t)b * H_N + (kg - Kin); ph = h_hi; pl = h_lo; }
      sa_h[it] = *(const short8*)(ph + o);
      sa_l[it] = *(const short8*)(pl + o);
    }
#pragma unroll
    for (int it = 0; it < 4; ++it) {  // B: 1024 granules (128 rows x 8)
      int G = it * 256 + tid;
      int r = G >> 3, gl = G & 7;
      int kg = (kc << 6) + (gl << 3);
      size_t o = (size_t)(tn * 128 + r) * Kl + kg;
      sb_h[it] = *(const short8*)(wl_hi + o);
      sb_l[it] = *(const short8*)(wl_lo + o);
    }
  };
  auto write_chunk = [&]() {
#pragma unroll
    for (int it = 0; it < 2; ++it) {
      int G = it * 256 + tid;
      int r = G >> 3, gl = G & 7;
      int idx = r * 64 + (gl ^ (r & 7)) * 8;   // XOR swizzle, 16B granules
      *(short8*)&Ahi[idx] = sa_h[it];
      *(short8*)&Alo[idx] = sa_l[it];
    }
#pragma unroll
    for (int it = 0; it < 4; ++it) {
      int G = it * 256 + tid;
      int r = G >> 3, gl = G & 7;
      int idx = r * 64 + (gl ^ (r & 7)) * 8;
      *(short8*)&Bhi[idx] = sb_h[it];
      *(short8*)&Blo[idx] = sb_l[it];
    }
  };

  const int nchunks = Kl >> 6;
  load_chunk(0);
  for (int kc = 0; kc < nchunks; ++kc) {
    __syncthreads();               // previous compute done reading LDS
    write_chunk();
    __syncthreads();
    if (kc + 1 < nchunks) load_chunk(kc + 1);  // overlap next-chunk HBM/L3 latency w/ MFMA

#pragma unroll
    for (int ks = 0; ks < 2; ++ks) {           // two K=32 MFMA steps per chunk
      const int glb = (ks << 2) + g16;         // logical k-granule for this lane group
      short8 ah[2], al[2], bh[4], bl[4];
#pragma unroll
      for (int mi = 0; mi < 2; ++mi) {
        int r = wave_m + mi * 16 + l15;
        int idx = r * 64 + (glb ^ (r & 7)) * 8;
        ah[mi] = *(const short8*)&Ahi[idx];
        al[mi] = *(const short8*)&Alo[idx];
      }
#pragma unroll
      for (int ni = 0; ni < 4; ++ni) {
        int r = wave_n + ni * 16 + l15;
        int idx = r * 64 + (glb ^ (r & 7)) * 8;
        bh[ni] = *(const short8*)&Bhi[idx];
        bl[ni] = *(const short8*)&Blo[idx];
      }
#pragma unroll
      for (int mi = 0; mi < 2; ++mi)
#pragma unroll
        for (int ni = 0; ni < 4; ++ni) {
          acc[mi][ni] = __builtin_amdgcn_mfma_f32_16x16x32_bf16(ah[mi], bh[ni], acc[mi][ni], 0, 0, 0);
          acc[mi][ni] = __builtin_amdgcn_mfma_f32_16x16x32_bf16(ah[mi], bl[ni], acc[mi][ni], 0, 0, 0);
          acc[mi][ni] = __builtin_amdgcn_mfma_f32_16x16x32_bf16(al[mi], bh[ni], acc[mi][ni], 0, 0, 0);
        }
    }
  }

  // epilogue: bias + tanh + hi/lo split, write h[t&1][l]
  const float* bias = (l == 0) ? b_ih0 : (b_ih_rest + (size_t)(l - 1) * H_N);
#pragma unroll
  for (int mi = 0; mi < 2; ++mi)
#pragma unroll
    for (int ni = 0; ni < 4; ++ni)
#pragma unroll
      for (int rg = 0; rg < 4; ++rg) {
        int bg = tm * 64 + wave_m + mi * 16 + g16 * 4 + rg;      // C/D: row = 4*(lane>>4)+reg
        int ng = tn * 128 + wave_n + ni * 16 + l15;              //      col = lane&15
        float v = acc[mi][ni][rg] + bias[ng];
        v = tanhf(v);
        u16 hi = f2bf(v);
        size_t o = ho_out + (size_t)bg * H_N + ng;
        h_hi[o] = hi;
        h_lo[o] = f2bf(v - bf2f(hi));
      }
}

// ---------------- final FC: out[b] = sum_h h_T^3[b][h]*W_fc[h] + b_fc ----------------
__global__ void fc_k(const u16* __restrict__ h_hi, const u16* __restrict__ h_lo,
                     const float* __restrict__ W_fc, const float* __restrict__ b_fc,
                     float* __restrict__ out) {
  int b = blockIdx.x, tid = threadIdx.x;
  size_t base = ((size_t)(((T_N - 1) & 1) * 4 + 3)) * HSLOT + (size_t)b * H_N;
  float s = 0.f;
  for (int j = tid; j < H_N; j += 256)
    s += (bf2f(h_hi[base + j]) + bf2f(h_lo[base + j])) * W_fc[j];
  __shared__ float red[256];
  red[tid] = s; __syncthreads();
  for (int w = 128; w > 0; w >>= 1) {
    if (tid < w) red[tid] += red[tid + w];
    __syncthreads();
  }
  if (tid == 0) out[b] = red[0] + b_fc[0];
}

extern "C" void kernel_launch(void* const* d_in, const int* in_sizes, int n_in,
                              void* d_out, int out_size, void* d_ws, size_t ws_size,
                              hipStream_t stream) {
  const float* x         = (const float*)d_in[0];
  const float* W_ih0     = (const float*)d_in[1];
  const float* b_ih0     = (const float*)d_in[2];
  const float* W_ih_rest = (const float*)d_in[3];
  const float* b_ih_rest = (const float*)d_in[4];
  const float* W_hh      = (const float*)d_in[5];
  const float* W_fc      = (const float*)d_in[6];
  const float* b_fc      = (const float*)d_in[7];
  float* out = (float*)d_out;

  char* p = (char*)d_ws;
  auto carve = [&](size_t bytes) {
    char* q = p; p += (bytes + 255) & ~(size_t)255; return q;
  };
  u16* wt_hi = (u16*)carve(WT_ELEMS * 2);
  u16* wt_lo = (u16*)carve(WT_ELEMS * 2);
  u16* xs_hi = (u16*)carve(XS_ELEMS * 2);
  u16* xs_lo = (u16*)carve(XS_ELEMS * 2);
  u16* h_hi  = (u16*)carve(H_ELEMS * 2);
  u16* h_lo  = (u16*)carve(H_ELEMS * 2);   // contiguous after h_hi

  // zero hidden state (t=-1 reads) each call; h_hi/h_lo are contiguous
  hipMemsetAsync(h_hi, 0, H_ELEMS * 2 * 2, stream);
  prep_w<<<4096, 256, 0, stream>>>(W_ih0, W_ih_rest, W_hh, wt_hi, wt_lo);
  prep_x<<<2048, 256, 0, stream>>>(x, xs_hi, xs_lo);

  for (int s = 0; s < T_N + L_N - 1; ++s)
    phase_k<<<256, 256, 0, stream>>>(wt_hi, wt_lo, xs_hi, xs_lo, h_hi, h_lo,
                                     b_ih0, b_ih_rest, s);

  fc_k<<<256, 256, 0, stream>>>(h_hi, h_lo, W_fc, b_fc, out);
}

// Round 5
// 16586.746 us; speedup vs baseline: 1.1608x; 1.1608x over previous
//
#include <hip/hip_runtime.h>
#include <hip/hip_bf16.h>

// RNN: B=256, T=256, I=64, H=2048, L=4, O=1
// h_t^l = tanh(W_ih^l @ inp + b_ih^l + W_hh^l @ h_{t-1}^l); out = h_T^{L-1} @ W_fc^T + b_fc
//
// bf16 hi/lo split-3 MFMA (fp32-grade accuracy), (t,l) anti-diagonal wavefront
// (259 phases), parity-double-buffered h.
// R5: m97-style schedule — NO inline asm / raw barriers (removes any hang risk;
// m97-verified structure). Double-buffered LDS + global_load_lds(16B) direct
// staging (XOR swizzle on SOURCE address, linear LDS dest, swizzled ds_read).
// Prefetch of chunk k+1 issued right after the top __syncthreads; its implicit
// vmcnt(0) next iteration is the drain, so HBM/L2 latency hides under compute.
// Tile 64x64, grid 512 = 2 blocks/CU -> inter-block overlap at every barrier.

typedef unsigned short u16;
typedef __attribute__((ext_vector_type(8))) short short8;
typedef __attribute__((ext_vector_type(4))) float f32x4;

#define T_N 256
#define I_N 64
#define H_N 2048
#define L_N 4

static constexpr size_t S0_ELE = 2048ull * 2112ull;           // layer0 combined W elems
static constexpr size_t SL_ELE = 2048ull * 4096ull;           // layers 1..3 each
static constexpr size_t WT_ELEMS = S0_ELE + 3ull * SL_ELE;    // 29,491,200
static constexpr size_t XS_ELEMS = 256ull * 256ull * 64ull;   // 4,194,304
static constexpr size_t HSLOT    = 256ull * 2048ull;          // one [B][H] slab
static constexpr size_t H_ELEMS  = 2ull * 4ull * HSLOT;       // parity x layer

__device__ __forceinline__ u16 f2bf(float v) {
  __hip_bfloat16 b = __float2bfloat16(v);
  u16 u; __builtin_memcpy(&u, &b, 2); return u;
}
__device__ __forceinline__ float bf2f(u16 u) {
  __hip_bfloat16 b; __builtin_memcpy(&b, &u, 2);
  return __bfloat162float(b);
}

// async 16B global -> LDS (lds dest is wave-uniform base; lane*16 is HW-added)
__device__ __forceinline__ void gl2lds16(const u16* g, u16* l) {
  __builtin_amdgcn_global_load_lds(
      (const __attribute__((address_space(1))) unsigned int*)g,
      (__attribute__((address_space(3))) unsigned int*)l, 16, 0, 0);
}

// ---------------- prep: split fp32 weights into bf16 hi/lo, k-concatenated [n][k] ----
__global__ void prep_w(const float* __restrict__ W_ih0, const float* __restrict__ W_ih_rest,
                       const float* __restrict__ W_hh,
                       u16* __restrict__ wt_hi, u16* __restrict__ wt_lo) {
  const unsigned TOT = (unsigned)WT_ELEMS;
  for (unsigned i = blockIdx.x * 256u + threadIdx.x; i < TOT; i += gridDim.x * 256u) {
    int l, K, Kin; unsigned r;
    if (i < (unsigned)S0_ELE) { l = 0; r = i; K = 2112; Kin = 64; }
    else {
      unsigned j = i - (unsigned)S0_ELE;
      l = 1 + (int)(j / (unsigned)SL_ELE);
      r = j % (unsigned)SL_ELE; K = 4096; Kin = 2048;
    }
    unsigned n = r / (unsigned)K, k = r % (unsigned)K;
    float v;
    if ((int)k < Kin)
      v = (l == 0) ? W_ih0[(size_t)n * 64 + k]
                   : W_ih_rest[(((size_t)(l - 1)) * 2048 + n) * 2048 + k];
    else
      v = W_hh[(((size_t)l) * 2048 + n) * 2048 + (k - (unsigned)Kin)];
    u16 hi = f2bf(v);
    wt_hi[i] = hi;
    wt_lo[i] = f2bf(v - bf2f(hi));
  }
}

__global__ void prep_x(const float* __restrict__ x, u16* __restrict__ xs_hi, u16* __restrict__ xs_lo) {
  for (unsigned i = blockIdx.x * 256u + threadIdx.x; i < (unsigned)XS_ELEMS; i += gridDim.x * 256u) {
    float v = x[i];
    u16 hi = f2bf(v);
    xs_hi[i] = hi;
    xs_lo[i] = f2bf(v - bf2f(hi));
  }
}

// ---------------- one wavefront phase: all (l, t=s-l) layer-GEMMs -------------------
// Block tile 64(M=batch) x 64(N=h). 4 waves, wave-tile 32x32. KC=64.
// LDS: 2 x (A 64x64 hi/lo + B 64x64 hi/lo) = 64KB -> 2 blocks/CU.
__launch_bounds__(256, 2)
__global__ void phase_k(const u16* __restrict__ wt_hi, const u16* __restrict__ wt_lo,
                        const u16* __restrict__ xs_hi, const u16* __restrict__ xs_lo,
                        u16* __restrict__ h_hi, u16* __restrict__ h_lo,
                        const float* __restrict__ b_ih0, const float* __restrict__ b_ih_rest,
                        int s) {
  // XCD-aware decode: the 4 m-blocks of one (n-tile, layer) share an XCD (L2 B-reuse)
  int bid = blockIdx.x;
  int xcd = bid & 7, slot = bid >> 3;          // slot 0..63
  int tm  = slot & 3;
  int tnl = (slot >> 2) & 3;
  int l   = slot >> 4;
  int tn  = xcd * 4 + tnl;                     // 0..31
  int t   = s - l;
  if (t < 0 || t >= T_N) return;

  const int Kl  = (l == 0) ? 2112 : 4096;
  const size_t woff = (l == 0) ? 0ull : (S0_ELE + (size_t)(l - 1) * SL_ELE);
  const u16* wl_hi = wt_hi + woff;
  const u16* wl_lo = wt_lo + woff;

  const size_t ho_out  = ((size_t)((t & 1) * 4 + l)) * HSLOT;
  const size_t ho_self = ((size_t)(((t - 1) & 1) * 4 + l)) * HSLOT;
  const int lprev = (l > 0) ? (l - 1) : 0;
  const size_t ho_prevL = ((size_t)((t & 1) * 4 + lprev)) * HSLOT;

  __shared__ __align__(16) u16 Ahi[2][64 * 64];
  __shared__ __align__(16) u16 Alo[2][64 * 64];
  __shared__ __align__(16) u16 Bhi[2][64 * 64];
  __shared__ __align__(16) u16 Blo[2][64 * 64];

  const int tid = threadIdx.x;
  const int lane = tid & 63;
  const int l15 = lane & 15, g16 = lane >> 4;
  const int wid = tid >> 6;
  const int wave_m = (wid & 1) * 32, wave_n = (wid >> 1) * 32;

  f32x4 acc[2][2];
#pragma unroll
  for (int mi = 0; mi < 2; ++mi)
#pragma unroll
    for (int ni = 0; ni < 2; ++ni)
      acc[mi][ni] = (f32x4){0.f, 0.f, 0.f, 0.f};

  const int selfc0 = (l == 0) ? 1 : 32;       // first K-chunk of the W_hh (h_self) region
  const int kin    = (l == 0) ? 64 : 2048;

  // Stage chunk kc into LDS buffer `buf`. Source granule is XOR-pre-swizzled
  // (gl ^ (r&7)); LDS dest is linear per wave (base + lane*16, HW-added).
  auto issue_chunk = [&](int kc, int buf) {
#pragma unroll
    for (int it = 0; it < 2; ++it) {          // A: 512 granules (64 rows x 8)
      int G = it * 256 + tid;
      int r = G >> 3, gl = G & 7;
      int kg = (kc << 6) + ((gl ^ (r & 7)) << 3);
      int b = tm * 64 + r;
      const u16 *ph, *pl; size_t o;
      if (kc < selfc0) {
        if (l == 0) { o = ((size_t)b * T_N + t) * I_N + kg; ph = xs_hi; pl = xs_lo; }
        else        { o = ho_prevL + (size_t)b * H_N + kg;  ph = h_hi;  pl = h_lo; }
      } else {
        o = ho_self + (size_t)b * H_N + (kg - kin); ph = h_hi; pl = h_lo;
      }
      u16* dh = &Ahi[buf][(it * 256 + wid * 64) * 8];   // wave-uniform dest base
      u16* dl = &Alo[buf][(it * 256 + wid * 64) * 8];
      gl2lds16(ph + o, dh);
      gl2lds16(pl + o, dl);
    }
#pragma unroll
    for (int it = 0; it < 2; ++it) {          // B: 512 granules (64 n-rows x 8)
      int G = it * 256 + tid;
      int r = G >> 3, gl = G & 7;
      size_t o = (size_t)(tn * 64 + r) * Kl + (kc << 6) + ((gl ^ (r & 7)) << 3);
      u16* dh = &Bhi[buf][(it * 256 + wid * 64) * 8];
      u16* dl = &Blo[buf][(it * 256 + wid * 64) * 8];
      gl2lds16(wl_hi + o, dh);
      gl2lds16(wl_lo + o, dl);
    }
  };

  const int nchunks = Kl >> 6;
  issue_chunk(0, 0);
  for (int kc = 0; kc < nchunks; ++kc) {
    const int cur = kc & 1;
    // Top barrier: implicit vmcnt(0) drain -> buf[cur] (issued last iter) ready;
    // also orders prior reads of buf[cur^1] before we overwrite it below.
    __syncthreads();
    if (kc + 1 < nchunks) issue_chunk(kc + 1, cur ^ 1);  // in flight during compute

#pragma unroll
    for (int ks = 0; ks < 2; ++ks) {           // two K=32 MFMA steps per chunk
      const int glb = (ks << 2) + g16;
      short8 ah[2], al[2], bh[2], bl[2];
#pragma unroll
      for (int mi = 0; mi < 2; ++mi) {
        int r = wave_m + mi * 16 + l15;
        int idx = r * 64 + ((glb ^ (r & 7)) << 3);
        ah[mi] = *(const short8*)&Ahi[cur][idx];
        al[mi] = *(const short8*)&Alo[cur][idx];
      }
#pragma unroll
      for (int ni = 0; ni < 2; ++ni) {
        int r = wave_n + ni * 16 + l15;
        int idx = r * 64 + ((glb ^ (r & 7)) << 3);
        bh[ni] = *(const short8*)&Bhi[cur][idx];
        bl[ni] = *(const short8*)&Blo[cur][idx];
      }
#pragma unroll
      for (int mi = 0; mi < 2; ++mi)
#pragma unroll
        for (int ni = 0; ni < 2; ++ni) {
          acc[mi][ni] = __builtin_amdgcn_mfma_f32_16x16x32_bf16(ah[mi], bh[ni], acc[mi][ni], 0, 0, 0);
          acc[mi][ni] = __builtin_amdgcn_mfma_f32_16x16x32_bf16(ah[mi], bl[ni], acc[mi][ni], 0, 0, 0);
          acc[mi][ni] = __builtin_amdgcn_mfma_f32_16x16x32_bf16(al[mi], bh[ni], acc[mi][ni], 0, 0, 0);
        }
    }
  }

  // epilogue: bias + tanh + hi/lo split, write h[t&1][l]
  const float* bias = (l == 0) ? b_ih0 : (b_ih_rest + (size_t)(l - 1) * H_N);
#pragma unroll
  for (int mi = 0; mi < 2; ++mi)
#pragma unroll
    for (int ni = 0; ni < 2; ++ni)
#pragma unroll
      for (int rg = 0; rg < 4; ++rg) {
        int bg = tm * 64 + wave_m + mi * 16 + g16 * 4 + rg;      // C/D: row = 4*(lane>>4)+reg
        int ng = tn * 64 + wave_n + ni * 16 + l15;               //      col = lane&15
        float v = acc[mi][ni][rg] + bias[ng];
        v = tanhf(v);
        u16 hi = f2bf(v);
        size_t o = ho_out + (size_t)bg * H_N + ng;
        h_hi[o] = hi;
        h_lo[o] = f2bf(v - bf2f(hi));
      }
}

// ---------------- final FC: out[b] = sum_h h_T^3[b][h]*W_fc[h] + b_fc ----------------
__global__ void fc_k(const u16* __restrict__ h_hi, const u16* __restrict__ h_lo,
                     const float* __restrict__ W_fc, const float* __restrict__ b_fc,
                     float* __restrict__ out) {
  int b = blockIdx.x, tid = threadIdx.x;
  size_t base = ((size_t)(((T_N - 1) & 1) * 4 + 3)) * HSLOT + (size_t)b * H_N;
  float s = 0.f;
  for (int j = tid; j < H_N; j += 256)
    s += (bf2f(h_hi[base + j]) + bf2f(h_lo[base + j])) * W_fc[j];
  __shared__ float red[256];
  red[tid] = s; __syncthreads();
  for (int w = 128; w > 0; w >>= 1) {
    if (tid < w) red[tid] += red[tid + w];
    __syncthreads();
  }
  if (tid == 0) out[b] = red[0] + b_fc[0];
}

extern "C" void kernel_launch(void* const* d_in, const int* in_sizes, int n_in,
                              void* d_out, int out_size, void* d_ws, size_t ws_size,
                              hipStream_t stream) {
  const float* x         = (const float*)d_in[0];
  const float* W_ih0     = (const float*)d_in[1];
  const float* b_ih0     = (const float*)d_in[2];
  const float* W_ih_rest = (const float*)d_in[3];
  const float* b_ih_rest = (const float*)d_in[4];
  const float* W_hh      = (const float*)d_in[5];
  const float* W_fc      = (const float*)d_in[6];
  const float* b_fc      = (const float*)d_in[7];
  float* out = (float*)d_out;

  char* p = (char*)d_ws;
  auto carve = [&](size_t bytes) {
    char* q = p; p += (bytes + 255) & ~(size_t)255; return q;
  };
  u16* wt_hi = (u16*)carve(WT_ELEMS * 2);
  u16* wt_lo = (u16*)carve(WT_ELEMS * 2);
  u16* xs_hi = (u16*)carve(XS_ELEMS * 2);
  u16* xs_lo = (u16*)carve(XS_ELEMS * 2);
  u16* h_hi  = (u16*)carve(H_ELEMS * 2);
  u16* h_lo  = (u16*)carve(H_ELEMS * 2);   // contiguous after h_hi

  // zero hidden state (t=-1 reads) each call; h_hi/h_lo are contiguous
  hipMemsetAsync(h_hi, 0, H_ELEMS * 2 * 2, stream);
  prep_w<<<4096, 256, 0, stream>>>(W_ih0, W_ih_rest, W_hh, wt_hi, wt_lo);
  prep_x<<<2048, 256, 0, stream>>>(x, xs_hi, xs_lo);

  for (int s = 0; s < T_N + L_N - 1; ++s)
    phase_k<<<512, 256, 0, stream>>>(wt_hi, wt_lo, xs_hi, xs_lo, h_hi, h_lo,
                                     b_ih0, b_ih_rest, s);

  fc_k<<<256, 256, 0, stream>>>(h_hi, h_lo, W_fc, b_fc, out);
}